// Round 9
// baseline (258.623 us; speedup 1.0000x reference)
//
#include <hip/hip_runtime.h>

// Problem constants: B=4, S=2048, D=1024
#define BB 4
#define SS 2048
#define DD 1024

typedef __attribute__((ext_vector_type(8))) _Float16 half8;
typedef __attribute__((ext_vector_type(4))) float f32x4;
typedef unsigned short ushort_t;

// fp32 -> fp16 (RTN via v_cvt_f16_f32), returned as raw bits
__device__ __forceinline__ ushort_t f2h(float f) {
    union { _Float16 h; ushort_t u; } c;
    c.h = (_Float16)f;
    return c.u;
}

union Pack8 { ushort_t u[8]; uint4 v; };

// ---------------------------------------------------------------------------
// K0: fp32 -> fp16 convert for BOTH Q(enc) and K(att) in one launch.
// ---------------------------------------------------------------------------
__global__ __launch_bounds__(256) void conv_h_qk(const float* __restrict__ enc,
                                                 const float* __restrict__ att,
                                                 ushort_t* __restrict__ Qb,
                                                 ushort_t* __restrict__ Kb) {
    const float* in = blockIdx.y ? att : enc;
    ushort_t* out   = blockIdx.y ? Kb : Qb;
    long i = ((long)blockIdx.x * 256 + threadIdx.x) * 8;
    float4 a = *(const float4*)(in + i);
    float4 b = *(const float4*)(in + i + 4);
    Pack8 p;
    p.u[0] = f2h(a.x); p.u[1] = f2h(a.y); p.u[2] = f2h(a.z); p.u[3] = f2h(a.w);
    p.u[4] = f2h(b.x); p.u[5] = f2h(b.y); p.u[6] = f2h(b.z); p.u[7] = f2h(b.w);
    *(uint4*)(out + i) = p.v;
}

// ---------------------------------------------------------------------------
// GEMM (bt form): C[m][n] = sum_k A[m][k] * B[n][k], A/B fp16 row-major,
// C fp32. PROVEN R6 structure (128x128 tile, BK=64, 4 waves, 16x16x32 f16
// MFMA, global_load_lds(16B), XOR swizzle, 0 bank conflicts) with one new
// addition: 1D grid + XCD-aware bijective block swizzle (T1). nwg % 8 == 0.
// ---------------------------------------------------------------------------
__global__ __launch_bounds__(256, 2)
void gemm_bt(const ushort_t* __restrict__ A, const ushort_t* __restrict__ Bm,
             float* __restrict__ C, int N, int Kd, int nmt, int nnt,
             long sAb, long sBb, long sCb) {
    __shared__ ushort_t Abuf[128 * 64];   // 16 KiB, row = 128 B
    __shared__ ushort_t Bbuf[128 * 64];   // 16 KiB

    const int t = threadIdx.x;
    const int w = t >> 6, lane = t & 63;
    const int wr = w >> 1, wc = w & 1;

    // XCD-aware bijective swizzle: consecutive lid round-robin XCDs; remap so
    // each XCD owns a contiguous chunk of tile space (L2 locality).
    const int nwg = gridDim.x;
    const int cpx = nwg >> 3;
    const int lid = blockIdx.x;
    const int swz = (lid & 7) * cpx + (lid >> 3);
    const int per_b = nmt * nnt;
    const int bz  = swz / per_b;
    const int rem = swz - bz * per_b;
    const int m0 = (rem / nnt) << 7;
    const int n0 = (rem % nnt) << 7;

    const ushort_t* Ab = A + (long)bz * sAb;
    const ushort_t* Bb = Bm + (long)bz * sBb;
    float* Cb = C + (long)bz * sCb;

    f32x4 zero = {0.f, 0.f, 0.f, 0.f};
    f32x4 acc[4][4];
    #pragma unroll
    for (int i = 0; i < 4; ++i)
        #pragma unroll
        for (int j = 0; j < 4; ++j) acc[i][j] = zero;

    const int rloc = lane >> 3;          // row within 8-row chunk
    const int rho  = (lane & 7) << 4;    // byte col within 128B row

    const int nkt = Kd >> 6;
    for (int kt = 0; kt < nkt; ++kt) {
        const int k0 = kt << 6;
        __syncthreads();  // previous compute done before LDS overwrite
        #pragma unroll
        for (int i = 0; i < 4; ++i) {
            int c = (w << 2) | i;              // chunk 0..15 (1 KiB each)
            int r = (c << 3) + rloc;           // tile row 0..127
            int rs = rho ^ ((r & 7) << 4);     // inverse-swizzled source col
            const char* src = (const char*)(Ab + (long)(m0 + r) * Kd + k0) + rs;
            __builtin_amdgcn_global_load_lds(
                (__attribute__((address_space(1))) void*)src,
                (__attribute__((address_space(3))) void*)((char*)Abuf + (c << 10)),
                16, 0, 0);
        }
        #pragma unroll
        for (int i = 0; i < 4; ++i) {
            int c = (w << 2) | i;
            int r = (c << 3) + rloc;
            int rs = rho ^ ((r & 7) << 4);
            const char* src = (const char*)(Bb + (long)(n0 + r) * Kd + k0) + rs;
            __builtin_amdgcn_global_load_lds(
                (__attribute__((address_space(1))) void*)src,
                (__attribute__((address_space(3))) void*)((char*)Bbuf + (c << 10)),
                16, 0, 0);
        }
        __syncthreads();  // drains vmcnt -> tile ready

        #pragma unroll
        for (int kk = 0; kk < 64; kk += 32) {
            const int colb = (kk + ((lane >> 4) << 3)) << 1;  // byte col base
            half8 af[4], bf[4];
            #pragma unroll
            for (int am = 0; am < 4; ++am) {
                int rA = (wr << 6) + (am << 4) + (lane & 15);
                int addr = (rA << 7) + (colb ^ ((rA & 7) << 4));
                af[am] = *(const half8*)((const char*)Abuf + addr);
            }
            #pragma unroll
            for (int bn = 0; bn < 4; ++bn) {
                int rB = (wc << 6) + (bn << 4) + (lane & 15);
                int addr = (rB << 7) + (colb ^ ((rB & 7) << 4));
                bf[bn] = *(const half8*)((const char*)Bbuf + addr);
            }
            #pragma unroll
            for (int am = 0; am < 4; ++am)
                #pragma unroll
                for (int bn = 0; bn < 4; ++bn)
                    acc[am][bn] = __builtin_amdgcn_mfma_f32_16x16x32_f16(
                        af[am], bf[bn], acc[am][bn], 0, 0, 0);
        }
    }

    // epilogue: D row = (lane>>4)*4 + j, col = lane&15  [m89 verified layout]
    #pragma unroll
    for (int am = 0; am < 4; ++am) {
        int mrow = m0 + (wr << 6) + (am << 4) + ((lane >> 4) << 2);
        #pragma unroll
        for (int bn = 0; bn < 4; ++bn) {
            int ncol = n0 + (wc << 6) + (bn << 4) + (lane & 15);
            #pragma unroll
            for (int j = 0; j < 4; ++j)
                Cb[(long)(mrow + j) * N + ncol] = acc[am][bn][j];
        }
    }
}

// ---------------------------------------------------------------------------
// Column softmax over score_T[b][k][q] (softmax along k for each column q).
// Split-k, 2 kernels, zero intra-block communication, fully coalesced.
// sm_part: block (qx, kc, b); thread owns column q = qx*256+t, processes
// k-chunk kc (256 rows), online (max, sum) -> partials pm/pz [B][8][SS].
// ---------------------------------------------------------------------------
__global__ __launch_bounds__(256) void sm_part(const float* __restrict__ st,
                                               float* __restrict__ pm,
                                               float* __restrict__ pz) {
    const int b = blockIdx.z, kc = blockIdx.y;
    const int q = (blockIdx.x << 8) + threadIdx.x;
    const float* base = st + ((long)b * SS + (kc << 8)) * SS + q;
    float m = -3.4e38f, Z = 0.f;
    #pragma unroll 8
    for (int k = 0; k < 256; ++k) {
        float v = base[(long)k * SS];
        float nm = fmaxf(m, v);
        Z = Z * __expf(m - nm) + __expf(v - nm);
        m = nm;
    }
    const long idx = ((long)b * 8 + kc) * SS + q;
    pm[idx] = m;
    pz[idx] = Z;
}

// sm_final: combine the 8 partials per column, then write this k-chunk of
// P^T as fp16: Pt[b][k][q] = exp(st[k][q]-m)/Z. Pt IS GEMM2's A operand.
__global__ __launch_bounds__(256) void sm_final(const float* __restrict__ st,
                                                const float* __restrict__ pm,
                                                const float* __restrict__ pz,
                                                ushort_t* __restrict__ Pt) {
    const int b = blockIdx.z, kc = blockIdx.y;
    const int q = (blockIdx.x << 8) + threadIdx.x;
    float m = -3.4e38f, Z = 0.f;
    #pragma unroll
    for (int c = 0; c < 8; ++c) {
        const long idx = ((long)b * 8 + c) * SS + q;
        float m2 = pm[idx], z2 = pz[idx];
        float nm = fmaxf(m, m2);
        Z = Z * __expf(m - nm) + z2 * __expf(m2 - nm);
        m = nm;
    }
    const float inv = 1.f / Z;
    const float* base = st + ((long)b * SS + (kc << 8)) * SS + q;
    ushort_t*    dst  = Pt + ((long)b * SS + (kc << 8)) * SS + q;
    #pragma unroll 8
    for (int k = 0; k < 256; ++k) {
        float v = base[(long)k * SS];
        dst[(long)k * SS] = f2h(__expf(v - m) * inv);
    }
}

// ---------------------------------------------------------------------------
// K4: Xbt[b][d][q] = fp16(enc[b][q][d] + res[b][q][d])
// ---------------------------------------------------------------------------
__global__ __launch_bounds__(256) void transposeX(const float* __restrict__ enc,
                                                  const float* __restrict__ res,
                                                  ushort_t* __restrict__ Xbt) {
    __shared__ ushort_t lds[64][72];
    const int b = blockIdx.z;
    const int q0 = blockIdx.x << 6, d0 = blockIdx.y << 6;
    const int t = threadIdx.x, rh = t >> 3, cb = (t & 7) << 3;

    #pragma unroll
    for (int it = 0; it < 2; ++it) {
        int r = (it << 5) + rh;
        long base = ((long)b * SS + q0 + r) * (long)DD + d0 + cb;
        float4 a0 = *(const float4*)(enc + base);
        float4 a1 = *(const float4*)(enc + base + 4);
        float4 b0 = *(const float4*)(res + base);
        float4 b1 = *(const float4*)(res + base + 4);
        Pack8 p;
        p.u[0] = f2h(a0.x + b0.x); p.u[1] = f2h(a0.y + b0.y);
        p.u[2] = f2h(a0.z + b0.z); p.u[3] = f2h(a0.w + b0.w);
        p.u[4] = f2h(a1.x + b1.x); p.u[5] = f2h(a1.y + b1.y);
        p.u[6] = f2h(a1.z + b1.z); p.u[7] = f2h(a1.w + b1.w);
        *(uint4*)&lds[r][cb] = p.v;
    }
    __syncthreads();
    #pragma unroll
    for (int it = 0; it < 2; ++it) {
        int rr = (it << 5) + rh;
        Pack8 p;
        #pragma unroll
        for (int j = 0; j < 8; ++j) p.u[j] = lds[cb + j][rr];
        *(uint4*)(Xbt + ((long)b * DD + d0 + rr) * (long)SS + q0 + cb) = p.v;
    }
}

// ---------------------------------------------------------------------------
// Workspace layout (96 MiB ws + d_out scratch, overlapped lifetimes):
//   ws [0, 64 MiB)   score_T fp32 [B][S_k][S_q] -> (after sm_final) Xbt fp16
//   ws [64, 96 MiB)  Qb fp16 [64,80) + Kb fp16 [80,96)  (dead after GEMM1)
//                    -> reused as Pt fp16 [B][S_k][S_q] (full 32 MiB)
//   d_out [0,512KiB) pm/pz partials (written by sm_part, read by sm_final,
//                    then fully overwritten by GEMM2's output)
// Stream ordering makes every overlap safe.
// ---------------------------------------------------------------------------
extern "C" void kernel_launch(void* const* d_in, const int* in_sizes, int n_in,
                              void* d_out, int out_size, void* d_ws, size_t ws_size,
                              hipStream_t stream) {
    const float* enc = (const float*)d_in[0];
    const float* att = (const float*)d_in[1];
    const float* res = (const float*)d_in[2];
    float* out = (float*)d_out;
    char* ws = (char*)d_ws;

    float*    score = (float*)ws;                            // 64 MiB
    ushort_t* Qb    = (ushort_t*)(ws + 67108864);            // 16 MiB
    ushort_t* Kb    = (ushort_t*)(ws + 83886080);            // 16 MiB
    ushort_t* Pt    = (ushort_t*)(ws + 67108864);            // overlays Qb+Kb (32 MiB)
    float*    pm    = (float*)d_out;                         // 256 KiB in d_out
    float*    pz    = ((float*)d_out) + 65536;               // 256 KiB in d_out
    ushort_t* Xbt   = (ushort_t*)ws;                         // overlays score

    // K0: convert Q (enc) and K (att) to fp16
    conv_h_qk<<<dim3(4096, 2), 256, 0, stream>>>(enc, att, Qb, Kb);

    // K1: score_T[b][k][q] = K[k,:].Q[q,:]  (swapped operands => transposed
    // scores for free; M=N=2048, Kd=1024; 16x16 tiles x 4 batches = 1024 wg)
    gemm_bt<<<1024, 256, 0, stream>>>(
        Kb, Qb, score, SS, DD, 16, 16,
        (long)SS * DD, (long)SS * DD, (long)SS * SS);

    // K2a/K2b: column softmax over k; writes Pt[b][k][q] fp16
    sm_part<<<dim3(8, 8, BB), 256, 0, stream>>>(score, pm, pz);
    sm_final<<<dim3(8, 8, BB), 256, 0, stream>>>(score, pm, pz, Pt);

    // K4: Xbt[b][d][q] = fp16(enc + res)   (score dead from here)
    transposeX<<<dim3(32, 16, BB), 256, 0, stream>>>(enc, res, Xbt);

    // K5: out[b][k][d] = sum_q Pt[k][q] * Xbt[d][q]
    // (M=2048, N=1024, Kd=2048; 16x8 tiles x 4 batches = 512 wg)
    gemm_bt<<<512, 256, 0, stream>>>(
        Pt, Xbt, out, DD, SS, 16, 8,
        (long)SS * SS, (long)DD * SS, (long)SS * DD);
}

// Round 13
// 236.745 us; speedup vs baseline: 1.0924x; 1.0924x over previous
//
#include <hip/hip_runtime.h>

// Problem constants: B=4, S=2048, D=1024
#define BB 4
#define SS 2048
#define DD 1024

typedef __attribute__((ext_vector_type(8))) _Float16 half8;
typedef __attribute__((ext_vector_type(4))) float f32x4;
typedef unsigned short ushort_t;

__device__ __forceinline__ ushort_t f2h(float f) {
    union { _Float16 h; ushort_t u; } c;
    c.h = (_Float16)f;
    return c.u;
}
__device__ __forceinline__ float h2f(ushort_t u) {
    union { ushort_t u; _Float16 h; } c;
    c.u = u;
    return (float)c.h;
}

union Pack8 { ushort_t u[8]; uint4 v; };

// ---------------------------------------------------------------------------
// K0 prep (FUSED): one pass over enc/att/res ->
//   Qb[b][q][d]  = fp16(enc)          (straight)
//   Kb[b][q][d]  = fp16(att)          (straight)
//   Xbt[b][d][q] = fp16(enc + res)    (transposed via LDS)
// 64x64 tiles; block (q0=bx*64, d0=by*64, b).
// ---------------------------------------------------------------------------
__global__ __launch_bounds__(256) void prep(const float* __restrict__ enc,
                                            const float* __restrict__ att,
                                            const float* __restrict__ res,
                                            ushort_t* __restrict__ Qb,
                                            ushort_t* __restrict__ Kb,
                                            ushort_t* __restrict__ Xbt) {
    __shared__ ushort_t lds[64][72];
    const int b = blockIdx.z;
    const int q0 = blockIdx.x << 6, d0 = blockIdx.y << 6;
    const int t = threadIdx.x, rh = t >> 3, cb = (t & 7) << 3;

    #pragma unroll
    for (int it = 0; it < 2; ++it) {
        int r = (it << 5) + rh;
        long base = ((long)b * SS + q0 + r) * (long)DD + d0 + cb;
        float4 e0 = *(const float4*)(enc + base);
        float4 e1 = *(const float4*)(enc + base + 4);
        float4 a0 = *(const float4*)(att + base);
        float4 a1 = *(const float4*)(att + base + 4);
        float4 r0 = *(const float4*)(res + base);
        float4 r1 = *(const float4*)(res + base + 4);
        Pack8 pq, pk, px;
        pq.u[0] = f2h(e0.x); pq.u[1] = f2h(e0.y); pq.u[2] = f2h(e0.z); pq.u[3] = f2h(e0.w);
        pq.u[4] = f2h(e1.x); pq.u[5] = f2h(e1.y); pq.u[6] = f2h(e1.z); pq.u[7] = f2h(e1.w);
        pk.u[0] = f2h(a0.x); pk.u[1] = f2h(a0.y); pk.u[2] = f2h(a0.z); pk.u[3] = f2h(a0.w);
        pk.u[4] = f2h(a1.x); pk.u[5] = f2h(a1.y); pk.u[6] = f2h(a1.z); pk.u[7] = f2h(a1.w);
        px.u[0] = f2h(e0.x + r0.x); px.u[1] = f2h(e0.y + r0.y);
        px.u[2] = f2h(e0.z + r0.z); px.u[3] = f2h(e0.w + r0.w);
        px.u[4] = f2h(e1.x + r1.x); px.u[5] = f2h(e1.y + r1.y);
        px.u[6] = f2h(e1.z + r1.z); px.u[7] = f2h(e1.w + r1.w);
        *(uint4*)(Qb + base) = pq.v;
        *(uint4*)(Kb + base) = pk.v;
        *(uint4*)&lds[r][cb] = px.v;
    }
    __syncthreads();
    #pragma unroll
    for (int it = 0; it < 2; ++it) {
        int rr = (it << 5) + rh;  // d-local
        Pack8 p;
        #pragma unroll
        for (int j = 0; j < 8; ++j) p.u[j] = lds[cb + j][rr];
        *(uint4*)(Xbt + ((long)b * DD + d0 + rr) * (long)SS + q0 + cb) = p.v;
    }
}

// ---------------------------------------------------------------------------
// GEMM (bt form): C[m][n] = sum_k A[m][k] * B[n][k], A/B fp16 row-major.
// EXACT round-6 proven structure (128x128 tile, BK=64, 4 waves, 16x16x32 f16
// MFMA, global_load_lds(16B), XOR swizzle, 0 bank conflicts, 2D grid).
// Template: HOUT=1 -> fp16 C (for score), HOUT=0 -> fp32 C (final out).
// ---------------------------------------------------------------------------
template<int HOUT>
__global__ __launch_bounds__(256, 2)
void gemm_bt(const ushort_t* __restrict__ A, const ushort_t* __restrict__ Bm,
             void* __restrict__ Cv, int N, int Kd,
             long sAb, long sBb, long sCb) {
    __shared__ ushort_t Abuf[128 * 64];   // 16 KiB, row = 128 B
    __shared__ ushort_t Bbuf[128 * 64];   // 16 KiB

    const int t = threadIdx.x;
    const int w = t >> 6, lane = t & 63;
    const int wr = w >> 1, wc = w & 1;
    const int m0 = blockIdx.x << 7;
    const int n0 = blockIdx.y << 7;
    const int bz = blockIdx.z;

    const ushort_t* Ab = A + (long)bz * sAb;
    const ushort_t* Bb = Bm + (long)bz * sBb;

    f32x4 zero = {0.f, 0.f, 0.f, 0.f};
    f32x4 acc[4][4];
    #pragma unroll
    for (int i = 0; i < 4; ++i)
        #pragma unroll
        for (int j = 0; j < 4; ++j) acc[i][j] = zero;

    const int rloc = lane >> 3;          // row within 8-row chunk
    const int rho  = (lane & 7) << 4;    // byte col within 128B row

    const int nkt = Kd >> 6;
    for (int kt = 0; kt < nkt; ++kt) {
        const int k0 = kt << 6;
        __syncthreads();  // previous compute done before LDS overwrite
        #pragma unroll
        for (int i = 0; i < 4; ++i) {
            int c = (w << 2) | i;              // chunk 0..15 (1 KiB each)
            int r = (c << 3) + rloc;           // tile row 0..127
            int rs = rho ^ ((r & 7) << 4);     // inverse-swizzled source col
            const char* src = (const char*)(Ab + (long)(m0 + r) * Kd + k0) + rs;
            __builtin_amdgcn_global_load_lds(
                (__attribute__((address_space(1))) void*)src,
                (__attribute__((address_space(3))) void*)((char*)Abuf + (c << 10)),
                16, 0, 0);
        }
        #pragma unroll
        for (int i = 0; i < 4; ++i) {
            int c = (w << 2) | i;
            int r = (c << 3) + rloc;
            int rs = rho ^ ((r & 7) << 4);
            const char* src = (const char*)(Bb + (long)(n0 + r) * Kd + k0) + rs;
            __builtin_amdgcn_global_load_lds(
                (__attribute__((address_space(1))) void*)src,
                (__attribute__((address_space(3))) void*)((char*)Bbuf + (c << 10)),
                16, 0, 0);
        }
        __syncthreads();  // drains vmcnt -> tile ready

        #pragma unroll
        for (int kk = 0; kk < 64; kk += 32) {
            const int colb = (kk + ((lane >> 4) << 3)) << 1;  // byte col base
            half8 af[4], bf[4];
            #pragma unroll
            for (int am = 0; am < 4; ++am) {
                int rA = (wr << 6) + (am << 4) + (lane & 15);
                int addr = (rA << 7) + (colb ^ ((rA & 7) << 4));
                af[am] = *(const half8*)((const char*)Abuf + addr);
            }
            #pragma unroll
            for (int bn = 0; bn < 4; ++bn) {
                int rB = (wc << 6) + (bn << 4) + (lane & 15);
                int addr = (rB << 7) + (colb ^ ((rB & 7) << 4));
                bf[bn] = *(const half8*)((const char*)Bbuf + addr);
            }
            #pragma unroll
            for (int am = 0; am < 4; ++am)
                #pragma unroll
                for (int bn = 0; bn < 4; ++bn)
                    acc[am][bn] = __builtin_amdgcn_mfma_f32_16x16x32_f16(
                        af[am], bf[bn], acc[am][bn], 0, 0, 0);
        }
    }

    // epilogue: D row = (lane>>4)*4 + j, col = lane&15  [m89 verified layout]
    #pragma unroll
    for (int am = 0; am < 4; ++am) {
        int mrow = m0 + (wr << 6) + (am << 4) + ((lane >> 4) << 2);
        #pragma unroll
        for (int bn = 0; bn < 4; ++bn) {
            int ncol = n0 + (wc << 6) + (bn << 4) + (lane & 15);
            if (HOUT) {
                ushort_t* Ch = (ushort_t*)Cv + (long)bz * sCb;
                #pragma unroll
                for (int j = 0; j < 4; ++j)
                    Ch[(long)(mrow + j) * N + ncol] = f2h(acc[am][bn][j]);
            } else {
                float* Cf = (float*)Cv + (long)bz * sCb;
                #pragma unroll
                for (int j = 0; j < 4; ++j)
                    Cf[(long)(mrow + j) * N + ncol] = acc[am][bn][j];
            }
        }
    }
}

// ---------------------------------------------------------------------------
// K2: row softmax over k (2048 fp16), fp32 math, write P fp16 in-place.
// One block per row; all reads complete before first barrier, write after
// last barrier (bytes [16t,16t+16)) — race-free.
// ---------------------------------------------------------------------------
__device__ __forceinline__ float wred_max(float v) {
    #pragma unroll
    for (int o = 32; o > 0; o >>= 1) v = fmaxf(v, __shfl_xor(v, o, 64));
    return v;
}
__device__ __forceinline__ float wred_sum(float v) {
    #pragma unroll
    for (int o = 32; o > 0; o >>= 1) v += __shfl_xor(v, o, 64);
    return v;
}

__global__ __launch_bounds__(256) void softmax_h(ushort_t* __restrict__ score) {
    __shared__ float red[4];
    __shared__ float bc[2];
    const long row = blockIdx.x;
    ushort_t* rp = score + row * (long)SS;
    const int t = threadIdx.x, w = t >> 6, lane = t & 63;

    Pack8 in;
    in.v = ((const uint4*)rp)[t];
    float f[8];
    #pragma unroll
    for (int j = 0; j < 8; ++j) f[j] = h2f(in.u[j]);

    float m = f[0];
    #pragma unroll
    for (int j = 1; j < 8; ++j) m = fmaxf(m, f[j]);
    m = wred_max(m);
    if (lane == 0) red[w] = m;
    __syncthreads();
    if (t == 0) bc[0] = fmaxf(fmaxf(red[0], red[1]), fmaxf(red[2], red[3]));
    __syncthreads();
    m = bc[0];

    float e[8], s = 0.f;
    #pragma unroll
    for (int j = 0; j < 8; ++j) { e[j] = __expf(f[j] - m); s += e[j]; }
    s = wred_sum(s);
    if (lane == 0) red[w] = s;
    __syncthreads();
    if (t == 0) bc[1] = red[0] + red[1] + red[2] + red[3];
    __syncthreads();
    const float inv = 1.f / bc[1];

    Pack8 p;
    #pragma unroll
    for (int j = 0; j < 8; ++j) p.u[j] = f2h(e[j] * inv);
    ((uint4*)rp)[t] = p.v;
}

// ---------------------------------------------------------------------------
// K3: transpose P (fp16, compact [B][S][S]): Pt[b][n][q] = P[b][q][n].
// ---------------------------------------------------------------------------
__global__ __launch_bounds__(256) void transposeP(const ushort_t* __restrict__ Pb,
                                                  ushort_t* __restrict__ Pt) {
    __shared__ ushort_t lds[64][72];
    const int b = blockIdx.z;
    const int n0 = blockIdx.x << 6, q0 = blockIdx.y << 6;
    const int t = threadIdx.x, rh = t >> 3, cb = (t & 7) << 3;

    #pragma unroll
    for (int it = 0; it < 2; ++it) {
        int r = (it << 5) + rh;
        const ushort_t* src = Pb + ((long)(b * SS + q0 + r)) * SS + n0 + cb;
        *(uint4*)&lds[r][cb] = *(const uint4*)src;
    }
    __syncthreads();
    #pragma unroll
    for (int it = 0; it < 2; ++it) {
        int rr = (it << 5) + rh;
        Pack8 p;
        #pragma unroll
        for (int j = 0; j < 8; ++j) p.u[j] = lds[cb + j][rr];
        *(uint4*)(Pt + ((long)b * SS + n0 + rr) * (long)SS + q0 + cb) = p.v;
    }
}

// ---------------------------------------------------------------------------
// Workspace layout (80 MiB, overlapped lifetimes):
//   [0, 32 MiB)   score fp16 [B][S][S] (GEMM1 out, softmax in-place)
//   [32, 48 MiB)  Qb fp16   -\ dead after GEMM1 -> Pt fp16 [B][S][S]
//   [48, 64 MiB)  Kb fp16   -/   occupies [32, 64 MiB)
//   [64, 80 MiB)  Xbt fp16 [B][D][S] (written by prep, read by GEMM2)
// Stream ordering makes every overlap safe.
// ---------------------------------------------------------------------------
extern "C" void kernel_launch(void* const* d_in, const int* in_sizes, int n_in,
                              void* d_out, int out_size, void* d_ws, size_t ws_size,
                              hipStream_t stream) {
    const float* enc = (const float*)d_in[0];
    const float* att = (const float*)d_in[1];
    const float* res = (const float*)d_in[2];
    char* ws = (char*)d_ws;

    ushort_t* score = (ushort_t*)ws;                         // 32 MiB
    ushort_t* Qb    = (ushort_t*)(ws + 33554432);            // 16 MiB
    ushort_t* Kb    = (ushort_t*)(ws + 50331648);            // 16 MiB
    ushort_t* Pt    = (ushort_t*)(ws + 33554432);            // overlays Qb+Kb
    ushort_t* Xbt   = (ushort_t*)(ws + 67108864);            // 16 MiB

    // K0: fused convert + transpose-add (reads enc/att/res exactly once)
    prep<<<dim3(32, 16, BB), 256, 0, stream>>>(enc, att, res, Qb, Kb, Xbt);

    // K1: score[b][q][k] = Q.K, fp16 out  (M=N=2048, Kd=1024)
    gemm_bt<1><<<dim3(16, 16, BB), 256, 0, stream>>>(
        Qb, Kb, (void*)score, SS, DD,
        (long)SS * DD, (long)SS * DD, (long)SS * SS);

    // K2: softmax rows (fp32 math), P fp16 in place
    softmax_h<<<BB * SS, 256, 0, stream>>>(score);

    // K3: Pt[b][k][q] = P[b][q][k]   (Qb/Kb dead from here)
    transposeP<<<dim3(32, 32, BB), 256, 0, stream>>>(score, Pt);

    // K5: out[b][k][d] = sum_q Pt[k][q] * Xbt[d][q], fp32 out
    // (M=2048, N=1024, Kd=2048)
    gemm_bt<0><<<dim3(16, 8, BB), 256, 0, stream>>>(
        Pt, Xbt, d_out, DD, SS,
        (long)SS * SS, (long)DD * SS, (long)SS * DD);
}